// Round 10
// baseline (244.674 us; speedup 1.0000x reference)
//
#include <hip/hip_runtime.h>
#include <hip/hip_bf16.h>

#define S_LEN 2048
#define DM 1024
#define NB 4

typedef __attribute__((ext_vector_type(8))) short short8;
typedef __attribute__((ext_vector_type(4))) short short4v;
typedef __attribute__((ext_vector_type(4))) float floatx4;

__device__ inline short f2bf(float f) {
    union { float f; unsigned u; } v; v.f = f;
    unsigned r = 0x7fffu + ((v.u >> 16) & 1u);
    return (short)((v.u + r) >> 16);
}

// async global->LDS 16B per lane; lds dest must be wave-uniform base (+lane*16 by HW)
__device__ inline void load16(const short* g, short* l) {
    __builtin_amdgcn_global_load_lds(
        (const __attribute__((address_space(1))) void*)g,
        (__attribute__((address_space(3))) void*)l,
        16, 0, 0);
}

// ---------------- BK=128 GEMM core ----------------
// C[128x128] = A[m0..,k] * Bt[n0..,k]^T, row-major bf16. 4 waves in 2x2,
// 4x4 tiles of 16x16x32 MFMA per wave, FOUR k-chunks per 128-wide K-iter:
// 64 MFMA per barrier drain. LDS tile 128 rows x 128 shorts (32 KB each).
// XOR swizzle: LDS chunk p (16 chunks of 8 shorts per row) of row r holds
// global chunk p^(r&15); frag chunk fc=4h+quad reads p=fc^l16 -> banks 2-way.
__device__ inline void gemm_core128(const short* __restrict__ A,
                                    const short* __restrict__ Bt,
                                    int lda, int ldb, int kLen,
                                    int m0, int n0, floatx4 acc[4][4],
                                    short* As, short* Bs) {
    const int tid  = threadIdx.x;
    const int lane = tid & 63;
    const int wave = tid >> 6;
    const int wr   = (wave >> 1) * 64;
    const int wc   = (wave & 1) * 64;
    const int quad = lane >> 4;
    const int l16  = lane & 15;

    // staging round c (0..7): row = c*16 + (tid>>4), LDS chunk p = tid&15,
    // global chunk g = p ^ (row&15) = (tid&15)^(tid>>4)  [round-invariant]
    const int srow = tid >> 4;
    const int g    = (tid & 15) ^ srow;
    const short* gA0 = A  + (size_t)(m0 + srow) * lda + g * 8;
    const short* gB0 = Bt + (size_t)(n0 + srow) * ldb + g * 8;
    short* lA0 = &As[wave * 512];   // round c adds c*2048 shorts
    short* lB0 = &Bs[wave * 512];

    const short* fa[4]; const short* fb[4];
#pragma unroll
    for (int h = 0; h < 4; h++) {
        int sw = ((h * 4 + quad) ^ l16) * 8;
        fa[h] = &As[(wr + l16) * 128 + sw];
        fb[h] = &Bs[(wc + l16) * 128 + sw];
    }

    for (int k0 = 0; k0 < kLen; k0 += 128) {
#pragma unroll
        for (int c = 0; c < 8; c++) load16(gA0 + (size_t)c * 16 * lda, lA0 + c * 2048);
#pragma unroll
        for (int c = 0; c < 8; c++) load16(gB0 + (size_t)c * 16 * ldb, lB0 + c * 2048);
        gA0 += 128; gB0 += 128;
        __syncthreads();

#pragma unroll
        for (int h = 0; h < 4; h++) {
            short8 af[4], bf[4];
#pragma unroll
            for (int t = 0; t < 4; t++) af[t] = *(const short8*)(fa[h] + t * 2048);
#pragma unroll
            for (int t = 0; t < 4; t++) bf[t] = *(const short8*)(fb[h] + t * 2048);
#pragma unroll
            for (int mt = 0; mt < 4; mt++)
#pragma unroll
                for (int nt = 0; nt < 4; nt++)
                    acc[mt][nt] = __builtin_amdgcn_mfma_f32_16x16x32_bf16(
                        af[mt], bf[nt], acc[mt][nt], 0, 0, 0);
        }
        __syncthreads();
    }
}

// ------- merged prep: Wt transpose+cast, x cast, denom zero, out-half zero -
__global__ void prep(const float* __restrict__ x,
                     const float* __restrict__ Wq, const float* __restrict__ Wk,
                     const float* __restrict__ Wv,
                     short* __restrict__ xb, short* __restrict__ Wt,
                     float* __restrict__ denom, float* __restrict__ out) {
    __shared__ float t[64][65];
    int bid = blockIdx.x, tid = threadIdx.x;
    if (bid < 768) {
        // W [k][n] fp32 -> Wt [n][k] bf16 (64x64 tiles)
        int w = bid >> 8, tl = bid & 255;
        const float* W = (w == 0) ? Wq : (w == 1) ? Wk : Wv;
        short* outw = Wt + (size_t)w * DM * DM;
        int bx = (tl & 15) * 64;   // n
        int by = (tl >> 4) * 64;   // k
        int tx = tid & 63, ty = tid >> 6;
        for (int r = ty; r < 64; r += 4)
            t[r][tx] = W[(size_t)(by + r) * DM + bx + tx];
        __syncthreads();
        for (int r = ty; r < 64; r += 4)
            outw[(size_t)(bx + r) * DM + by + tx] = f2bf(t[tx][r]);
    } else if (bid < 768 + 8192) {
        // x fp32 -> bf16, float4-wide
        int i = (bid - 768) * 256 + tid;
        float4 v = ((const float4*)x)[i];
        short4v o;
        o.x = f2bf(v.x); o.y = f2bf(v.y); o.z = f2bf(v.z); o.w = f2bf(v.w);
        ((short4v*)xb)[i] = o;
    } else if (bid < 8992) {
        int i = (bid - 8960) * 256 + tid;
        if (i < NB * S_LEN) denom[i] = 0.f;
    } else {
        // zero out rows >= 1024 per batch (atomicAdd targets of split-K pv):
        // 16 MB = 1M float4 over 2048 blocks x 512 f4
        int vb = bid - 8992;
#pragma unroll
        for (int k = 0; k < 2; k++) {
            int idx = vb * 512 + k * 256 + tid;          // 0..2^20-1
            int b   = idx >> 18;                          // 256K f4 per batch
            int off = idx & 262143;
            float4* p = (float4*)(out + (size_t)b * S_LEN * DM + 1024 * DM);
            p[off] = (float4){0.f, 0.f, 0.f, 0.f};
        }
    }
}

// ---------------- fused QKV GEMM, BK=64 (unchanged, ~936 TF) ----------------
__global__ __launch_bounds__(256, 2)
void qkv_fused(const short* __restrict__ xb, const short* __restrict__ Wt,
               const float* __restrict__ bq, const float* __restrict__ bk,
               const float* __restrict__ bv,
               short* __restrict__ Qb, short* __restrict__ Kb,
               short* __restrict__ Vtb) {
    __shared__ short As[8192];        // 128x64 staging; also V-transpose buf (4608)
    __shared__ short Bs[3 * 8192];
    int n0 = blockIdx.x * 128;
    int m0 = blockIdx.y * 128;

    const int tid  = threadIdx.x;
    const int lane = tid & 63;
    const int wave = tid >> 6;
    const int wr   = (wave >> 1) * 64;
    const int wc   = (wave & 1) * 64;
    const int quad = lane >> 4;
    const int l16  = lane & 15;

    floatx4 acc[3][4][4];
#pragma unroll
    for (int w = 0; w < 3; w++)
#pragma unroll
        for (int i = 0; i < 4; i++)
#pragma unroll
            for (int j = 0; j < 4; j++) acc[w][i][j] = (floatx4){0.f, 0.f, 0.f, 0.f};

    const short* gA[4]; const short* gW[4];
    short* lA[4]; short* lB[4];
#pragma unroll
    for (int c = 0; c < 4; c++) {
        int idx = c * 256 + tid;
        int row = idx >> 3;
        int g = (idx & 7) ^ (row & 7);
        gA[c] = xb + (size_t)(m0 + row) * DM + g * 8;
        gW[c] = Wt + (size_t)(n0 + row) * DM + g * 8;
        int lbase = (c * 256 + wave * 64) * 8;
        lA[c] = &As[lbase];
        lB[c] = &Bs[lbase];
    }

    const short* fa[2]; const short* fb[2];
#pragma unroll
    for (int h = 0; h < 2; h++) {
        int sw = ((h * 4 + quad) ^ (l16 & 7)) * 8;
        fa[h] = &As[(wr + l16) * 64 + sw];
        fb[h] = &Bs[(wc + l16) * 64 + sw];
    }

    for (int k0 = 0; k0 < DM; k0 += 64) {
#pragma unroll
        for (int c = 0; c < 4; c++) load16(gA[c], lA[c]);
#pragma unroll
        for (int w = 0; w < 3; w++)
#pragma unroll
            for (int c = 0; c < 4; c++)
                load16(gW[c] + (size_t)w * DM * DM, lB[c] + w * 8192);
#pragma unroll
        for (int c = 0; c < 4; c++) { gA[c] += 64; gW[c] += 64; }
        __syncthreads();

#pragma unroll
        for (int h = 0; h < 2; h++) {
            short8 af[4];
#pragma unroll
            for (int t = 0; t < 4; t++) af[t] = *(const short8*)(fa[h] + t * 1024);
#pragma unroll
            for (int w = 0; w < 3; w++) {
                short8 bf[4];
#pragma unroll
                for (int t = 0; t < 4; t++)
                    bf[t] = *(const short8*)(fb[h] + w * 8192 + t * 1024);
#pragma unroll
                for (int mt = 0; mt < 4; mt++)
#pragma unroll
                    for (int nt = 0; nt < 4; nt++)
                        acc[w][mt][nt] = __builtin_amdgcn_mfma_f32_16x16x32_bf16(
                            af[mt], bf[nt], acc[w][mt][nt], 0, 0, 0);
            }
        }
        __syncthreads();
    }

    // ---- Q and K epilogues (direct row-major store) ----
#pragma unroll
    for (int w = 0; w < 2; w++) {
        short* out = w ? Kb : Qb;
        const float* bias = w ? bk : bq;
        float scale = w ? 1.0f : 0.03125f;   // fold 1/sqrt(1024) into Q
#pragma unroll
        for (int mt = 0; mt < 4; mt++)
#pragma unroll
            for (int nt = 0; nt < 4; nt++) {
                int col = n0 + wc + nt * 16 + l16;
                float bv_ = bias[col];
#pragma unroll
                for (int r = 0; r < 4; r++) {
                    int row = m0 + wr + mt * 16 + quad * 4 + r;
                    out[(size_t)row * DM + col] = f2bf((acc[w][mt][nt][r] + bv_) * scale);
                }
            }
    }

    // ---- V epilogue: write V^T into Vtb[b][d][s] via per-wave 64x64 LDS pass ----
    {
        int b = m0 >> 11;
        int sbase = (m0 & 2047) + wr;
        float bvv[4];
#pragma unroll
        for (int nt = 0; nt < 4; nt++) bvv[nt] = bv[n0 + wc + nt * 16 + l16];
        short* buf = (wave & 1) ? Bs : As;   // 64 d-rows x 72 (stride 144B, 16B-aligned)
        short* vt = Vtb + ((size_t)b * DM + n0 + wc) * S_LEN;
#pragma unroll
        for (int p = 0; p < 2; p++) {
            __syncthreads();
            if ((wave >> 1) == p) {
#pragma unroll
                for (int mt = 0; mt < 4; mt++)
#pragma unroll
                    for (int nt = 0; nt < 4; nt++) {
                        int c = nt * 16 + l16;
                        short4v pk;
                        pk.x = f2bf(acc[2][mt][nt][0] + bvv[nt]);
                        pk.y = f2bf(acc[2][mt][nt][1] + bvv[nt]);
                        pk.z = f2bf(acc[2][mt][nt][2] + bvv[nt]);
                        pk.w = f2bf(acc[2][mt][nt][3] + bvv[nt]);
                        *(short4v*)&buf[c * 72 + mt * 16 + quad * 4] = pk;
                    }
                asm volatile("s_waitcnt lgkmcnt(0)" ::: "memory");
#pragma unroll
                for (int ps = 0; ps < 8; ps++) {
                    int dl = ps * 8 + (lane >> 3);
                    int sl = (lane & 7) * 8;
                    short8 row = *(short8*)&buf[dl * 72 + sl];
                    *(short8*)(vt + (size_t)dl * S_LEN + sbase + sl) = row;
                }
            }
        }
    }
}

// scores -> P = exp(s) (bf16, causal-masked) + per-row denom accumulation.
// BK=128; heavy-first dispatch (xq reversed -> it descending within each batch)
// so the 32 non-resident straggler blocks are the 1-iter it=0 tiles.
__global__ __launch_bounds__(256, 2)
void score_gemm(const short* __restrict__ Qb, const short* __restrict__ Kb,
                short* __restrict__ P, float* __restrict__ denom) {
    __shared__ short As[16384];
    __shared__ short Bs[16384];
    int b = blockIdx.z;
    int xq = 135 - (int)blockIdx.x;    // heavy-first
    int it = (int)((sqrtf(8.0f * xq + 1.0f) - 1.0f) * 0.5f);
    while ((it + 1) * (it + 2) / 2 <= xq) it++;
    while (it * (it + 1) / 2 > xq) it--;
    int jt = xq - it * (it + 1) / 2;
    int n0 = jt * 128, m0 = it * 128;
    const short* A  = Qb + (size_t)b * S_LEN * DM;
    const short* Bt = Kb + (size_t)b * S_LEN * DM;

    floatx4 acc[4][4];
#pragma unroll
    for (int i = 0; i < 4; i++)
#pragma unroll
        for (int j = 0; j < 4; j++) acc[i][j] = (floatx4){0.f, 0.f, 0.f, 0.f};

    gemm_core128(A, Bt, DM, DM, DM, m0, n0, acc, As, Bs);

    short* out = P + (size_t)b * S_LEN * S_LEN;
    float* dsum = denom + (size_t)b * S_LEN;
    const int lane = threadIdx.x & 63, wave = threadIdx.x >> 6;
    const int wr = (wave >> 1) * 64, wc = (wave & 1) * 64;
    const int quad = lane >> 4, l16 = lane & 15;
    const bool diag = (jt == it);
#pragma unroll
    for (int mt = 0; mt < 4; mt++) {
#pragma unroll
        for (int r = 0; r < 4; r++) {
            int row = m0 + wr + mt * 16 + quad * 4 + r;
            float psum = 0.f;
#pragma unroll
            for (int nt = 0; nt < 4; nt++) {
                int col = n0 + wc + nt * 16 + l16;
                float e = __expf(acc[mt][nt][r]);
                if (diag && col > row) e = 0.f;
                out[(size_t)row * S_LEN + col] = f2bf(e);
                psum += e;
            }
#pragma unroll
            for (int off = 8; off > 0; off >>= 1)
                psum += __shfl_down(psum, off, 16);
            if (l16 == 0) atomicAdd(&dsum[row], psum);
        }
    }
}

// ---------------- PV GEMM, BK=128, split-K for it>=8 ----------------
// 768 blocks = 24 classes x 32 (b,dc). Classes sorted descending by K-iters so
// co-residency (512) takes the heavy ones first. it>=8 splits its (it+1) iters
// ceil/floor across hf=0/1 and accumulates via fp32 atomicAdd (rows pre-zeroed
// in prep); it<8 (hf==2) does the full range with plain stores.
__global__ __launch_bounds__(256, 2)
void pv_gemm(const short* __restrict__ P, const short* __restrict__ Vtb,
             const float* __restrict__ denom, float* __restrict__ O) {
    __shared__ short As[16384];
    __shared__ short Bs[16384];
    static const int ITB[24] = {15,15,14, 7,14,13,13,12, 6,12,11,11,10, 5,10, 9, 9, 8, 4, 8, 3, 2, 1, 0};
    static const int HFB[24] = { 0, 1, 0, 2, 1, 0, 1, 0, 2, 1, 0, 1, 0, 2, 1, 0, 1, 0, 2, 1, 2, 2, 2, 2};
    int bid = blockIdx.x;
    int cls = bid >> 5;
    int sub = bid & 31;
    int it = ITB[cls], hf = HFB[cls];
    int b  = sub & 3;
    int n0 = (sub >> 2) * 128;         // d
    int m0 = it * 128;
    int nIt   = it + 1;                // total BK=128 iters for this q-tile
    int cIt   = (nIt + 1) >> 1;        // ceil half
    int iters = (hf == 2) ? nIt : (hf == 0 ? cIt : nIt - cIt);
    int koff  = (hf == 1) ? cIt * 128 : 0;
    const short* A  = P   + (size_t)b * S_LEN * S_LEN + koff;
    const short* Bt = Vtb + (size_t)b * DM * S_LEN + koff;

    floatx4 acc[4][4];
#pragma unroll
    for (int i = 0; i < 4; i++)
#pragma unroll
        for (int j = 0; j < 4; j++) acc[i][j] = (floatx4){0.f, 0.f, 0.f, 0.f};

    gemm_core128(A, Bt, S_LEN, S_LEN, iters * 128, m0, n0, acc, As, Bs);

    float* out = O + (size_t)b * S_LEN * DM;
    const float* dsum = denom + (size_t)b * S_LEN;
    const int lane = threadIdx.x & 63, wave = threadIdx.x >> 6;
    const int wr = (wave >> 1) * 64, wc = (wave & 1) * 64;
    const int quad = lane >> 4, l16 = lane & 15;
#pragma unroll
    for (int mt = 0; mt < 4; mt++) {
#pragma unroll
        for (int r = 0; r < 4; r++) {
            int row = m0 + wr + mt * 16 + quad * 4 + r;
            float inv = 1.0f / dsum[row];
#pragma unroll
            for (int nt = 0; nt < 4; nt++) {
                int col = n0 + wc + nt * 16 + l16;
                float val = acc[mt][nt][r] * inv;
                if (hf == 2) out[(size_t)row * DM + col] = val;
                else         atomicAdd(&out[(size_t)row * DM + col], val);
            }
        }
    }
}

// ---------------- launch ----------------
extern "C" void kernel_launch(void* const* d_in, const int* in_sizes, int n_in,
                              void* d_out, int out_size, void* d_ws, size_t ws_size,
                              hipStream_t stream) {
    const float* x  = (const float*)d_in[0];
    const float* Wq = (const float*)d_in[1];
    const float* bq = (const float*)d_in[2];
    const float* Wk = (const float*)d_in[3];
    const float* bk = (const float*)d_in[4];
    const float* Wv = (const float*)d_in[5];
    const float* bv = (const float*)d_in[6];
    float* out = (float*)d_out;

    char* ws = (char*)d_ws;
    const size_t MB = 1u << 20;
    short* xb    = (short*)(ws + 0);          // 16 MB  [8192][1024] bf16
    short* Wt    = (short*)(ws + 16 * MB);    //  6 MB  [3][1024][1024] bf16 (n-major)
    short* Qb    = (short*)(ws + 22 * MB);    // 16 MB
    short* Kb    = (short*)(ws + 38 * MB);    // 16 MB
    short* Vtb   = (short*)(ws + 54 * MB);    // 16 MB  [b][d][s]
    short* P     = (short*)(ws + 70 * MB);    // 32 MB  [b][s][s] bf16 = exp(s)
    float* denom = (float*)(ws + 102 * MB);   // 32 KB  [b][s] fp32 row sums
    // total ~102 MB

    prep<<<dim3(11040), dim3(256), 0, stream>>>(x, Wq, Wk, Wv, xb, Wt, denom, out);
    qkv_fused<<<dim3(8, 64), dim3(256), 0, stream>>>(xb, Wt, bq, bk, bv, Qb, Kb, Vtb);
    score_gemm<<<dim3(136, 1, NB), dim3(256), 0, stream>>>(Qb, Kb, P, denom);
    pv_gemm<<<dim3(768), dim3(256), 0, stream>>>(P, Vtb, denom, out);
}

// Round 11
// 219.387 us; speedup vs baseline: 1.1153x; 1.1153x over previous
//
#include <hip/hip_runtime.h>
#include <hip/hip_bf16.h>

#define S_LEN 2048
#define DM 1024
#define NB 4

typedef __attribute__((ext_vector_type(8))) short short8;
typedef __attribute__((ext_vector_type(4))) short short4v;
typedef __attribute__((ext_vector_type(4))) float floatx4;

__device__ inline short f2bf(float f) {
    union { float f; unsigned u; } v; v.f = f;
    unsigned r = 0x7fffu + ((v.u >> 16) & 1u);
    return (short)((v.u + r) >> 16);
}

// async global->LDS 16B per lane; lds dest must be wave-uniform base (+lane*16 by HW)
__device__ inline void load16(const short* g, short* l) {
    __builtin_amdgcn_global_load_lds(
        (const __attribute__((address_space(1))) void*)g,
        (__attribute__((address_space(3))) void*)l,
        16, 0, 0);
}

// ---------------- BK=128 GEMM core ----------------
// C[128x128] = A[m0..,k] * Bt[n0..,k]^T, row-major bf16. 4 waves in 2x2,
// 4x4 tiles of 16x16x32 MFMA per wave, FOUR k-chunks per 128-wide K-iter:
// 64 MFMA per barrier drain. LDS tile 128 rows x 128 shorts (32 KB each).
// XOR swizzle: LDS chunk p (16 chunks of 8 shorts per row) of row r holds
// global chunk p^(r&15); frag chunk fc=4h+quad reads p=fc^l16 -> banks 2-way.
__device__ inline void gemm_core128(const short* __restrict__ A,
                                    const short* __restrict__ Bt,
                                    int lda, int ldb, int kLen,
                                    int m0, int n0, floatx4 acc[4][4],
                                    short* As, short* Bs) {
    const int tid  = threadIdx.x;
    const int lane = tid & 63;
    const int wave = tid >> 6;
    const int wr   = (wave >> 1) * 64;
    const int wc   = (wave & 1) * 64;
    const int quad = lane >> 4;
    const int l16  = lane & 15;

    // staging round c (0..7): row = c*16 + (tid>>4), LDS chunk p = tid&15,
    // global chunk g = p ^ (row&15) = (tid&15)^(tid>>4)  [round-invariant]
    const int srow = tid >> 4;
    const int g    = (tid & 15) ^ srow;
    const short* gA0 = A  + (size_t)(m0 + srow) * lda + g * 8;
    const short* gB0 = Bt + (size_t)(n0 + srow) * ldb + g * 8;
    short* lA0 = &As[wave * 512];   // round c adds c*2048 shorts
    short* lB0 = &Bs[wave * 512];

    const short* fa[4]; const short* fb[4];
#pragma unroll
    for (int h = 0; h < 4; h++) {
        int sw = ((h * 4 + quad) ^ l16) * 8;
        fa[h] = &As[(wr + l16) * 128 + sw];
        fb[h] = &Bs[(wc + l16) * 128 + sw];
    }

    for (int k0 = 0; k0 < kLen; k0 += 128) {
#pragma unroll
        for (int c = 0; c < 8; c++) load16(gA0 + (size_t)c * 16 * lda, lA0 + c * 2048);
#pragma unroll
        for (int c = 0; c < 8; c++) load16(gB0 + (size_t)c * 16 * ldb, lB0 + c * 2048);
        gA0 += 128; gB0 += 128;
        __syncthreads();

#pragma unroll
        for (int h = 0; h < 4; h++) {
            short8 af[4], bf[4];
#pragma unroll
            for (int t = 0; t < 4; t++) af[t] = *(const short8*)(fa[h] + t * 2048);
#pragma unroll
            for (int t = 0; t < 4; t++) bf[t] = *(const short8*)(fb[h] + t * 2048);
#pragma unroll
            for (int mt = 0; mt < 4; mt++)
#pragma unroll
                for (int nt = 0; nt < 4; nt++)
                    acc[mt][nt] = __builtin_amdgcn_mfma_f32_16x16x32_bf16(
                        af[mt], bf[nt], acc[mt][nt], 0, 0, 0);
        }
        __syncthreads();
    }
}

// ---------------- merged prep: Wt transpose+cast, x cast, denom zero -------
__global__ void prep(const float* __restrict__ x,
                     const float* __restrict__ Wq, const float* __restrict__ Wk,
                     const float* __restrict__ Wv,
                     short* __restrict__ xb, short* __restrict__ Wt,
                     float* __restrict__ denom) {
    __shared__ float t[64][65];
    int bid = blockIdx.x, tid = threadIdx.x;
    if (bid < 768) {
        // W [k][n] fp32 -> Wt [n][k] bf16 (64x64 tiles)
        int w = bid >> 8, tl = bid & 255;
        const float* W = (w == 0) ? Wq : (w == 1) ? Wk : Wv;
        short* out = Wt + (size_t)w * DM * DM;
        int bx = (tl & 15) * 64;   // n
        int by = (tl >> 4) * 64;   // k
        int tx = tid & 63, ty = tid >> 6;
        for (int r = ty; r < 64; r += 4)
            t[r][tx] = W[(size_t)(by + r) * DM + bx + tx];
        __syncthreads();
        for (int r = ty; r < 64; r += 4)
            out[(size_t)(bx + r) * DM + by + tx] = f2bf(t[tx][r]);
    } else if (bid < 768 + 8192) {
        // x fp32 -> bf16, float4-wide
        int i = (bid - 768) * 256 + tid;
        float4 v = ((const float4*)x)[i];
        short4v o;
        o.x = f2bf(v.x); o.y = f2bf(v.y); o.z = f2bf(v.z); o.w = f2bf(v.w);
        ((short4v*)xb)[i] = o;
    } else {
        int i = (bid - 8960) * 256 + tid;
        if (i < NB * S_LEN) denom[i] = 0.f;
    }
}

// ---------------- fused QKV GEMM, BK=64 (unchanged, ~936 TF) ----------------
__global__ __launch_bounds__(256, 2)
void qkv_fused(const short* __restrict__ xb, const short* __restrict__ Wt,
               const float* __restrict__ bq, const float* __restrict__ bk,
               const float* __restrict__ bv,
               short* __restrict__ Qb, short* __restrict__ Kb,
               short* __restrict__ Vtb) {
    __shared__ short As[8192];        // 128x64 staging; also V-transpose buf (4608)
    __shared__ short Bs[3 * 8192];
    int n0 = blockIdx.x * 128;
    int m0 = blockIdx.y * 128;

    const int tid  = threadIdx.x;
    const int lane = tid & 63;
    const int wave = tid >> 6;
    const int wr   = (wave >> 1) * 64;
    const int wc   = (wave & 1) * 64;
    const int quad = lane >> 4;
    const int l16  = lane & 15;

    floatx4 acc[3][4][4];
#pragma unroll
    for (int w = 0; w < 3; w++)
#pragma unroll
        for (int i = 0; i < 4; i++)
#pragma unroll
            for (int j = 0; j < 4; j++) acc[w][i][j] = (floatx4){0.f, 0.f, 0.f, 0.f};

    const short* gA[4]; const short* gW[4];
    short* lA[4]; short* lB[4];
#pragma unroll
    for (int c = 0; c < 4; c++) {
        int idx = c * 256 + tid;
        int row = idx >> 3;
        int g = (idx & 7) ^ (row & 7);
        gA[c] = xb + (size_t)(m0 + row) * DM + g * 8;
        gW[c] = Wt + (size_t)(n0 + row) * DM + g * 8;
        int lbase = (c * 256 + wave * 64) * 8;
        lA[c] = &As[lbase];
        lB[c] = &Bs[lbase];
    }

    const short* fa[2]; const short* fb[2];
#pragma unroll
    for (int h = 0; h < 2; h++) {
        int sw = ((h * 4 + quad) ^ (l16 & 7)) * 8;
        fa[h] = &As[(wr + l16) * 64 + sw];
        fb[h] = &Bs[(wc + l16) * 64 + sw];
    }

    for (int k0 = 0; k0 < DM; k0 += 64) {
#pragma unroll
        for (int c = 0; c < 4; c++) load16(gA[c], lA[c]);
#pragma unroll
        for (int w = 0; w < 3; w++)
#pragma unroll
            for (int c = 0; c < 4; c++)
                load16(gW[c] + (size_t)w * DM * DM, lB[c] + w * 8192);
#pragma unroll
        for (int c = 0; c < 4; c++) { gA[c] += 64; gW[c] += 64; }
        __syncthreads();

#pragma unroll
        for (int h = 0; h < 2; h++) {
            short8 af[4];
#pragma unroll
            for (int t = 0; t < 4; t++) af[t] = *(const short8*)(fa[h] + t * 1024);
#pragma unroll
            for (int w = 0; w < 3; w++) {
                short8 bf[4];
#pragma unroll
                for (int t = 0; t < 4; t++)
                    bf[t] = *(const short8*)(fb[h] + w * 8192 + t * 1024);
#pragma unroll
                for (int mt = 0; mt < 4; mt++)
#pragma unroll
                    for (int nt = 0; nt < 4; nt++)
                        acc[w][mt][nt] = __builtin_amdgcn_mfma_f32_16x16x32_bf16(
                            af[mt], bf[nt], acc[w][mt][nt], 0, 0, 0);
            }
        }
        __syncthreads();
    }

    // ---- Q and K epilogues (direct row-major store) ----
#pragma unroll
    for (int w = 0; w < 2; w++) {
        short* out = w ? Kb : Qb;
        const float* bias = w ? bk : bq;
        float scale = w ? 1.0f : 0.03125f;   // fold 1/sqrt(1024) into Q
#pragma unroll
        for (int mt = 0; mt < 4; mt++)
#pragma unroll
            for (int nt = 0; nt < 4; nt++) {
                int col = n0 + wc + nt * 16 + l16;
                float bv_ = bias[col];
#pragma unroll
                for (int r = 0; r < 4; r++) {
                    int row = m0 + wr + mt * 16 + quad * 4 + r;
                    out[(size_t)row * DM + col] = f2bf((acc[w][mt][nt][r] + bv_) * scale);
                }
            }
    }

    // ---- V epilogue: write V^T into Vtb[b][d][s] via per-wave 64x64 LDS pass ----
    {
        int b = m0 >> 11;
        int sbase = (m0 & 2047) + wr;
        float bvv[4];
#pragma unroll
        for (int nt = 0; nt < 4; nt++) bvv[nt] = bv[n0 + wc + nt * 16 + l16];
        short* buf = (wave & 1) ? Bs : As;   // 64 d-rows x 72 (stride 144B, 16B-aligned)
        short* vt = Vtb + ((size_t)b * DM + n0 + wc) * S_LEN;
#pragma unroll
        for (int p = 0; p < 2; p++) {
            __syncthreads();
            if ((wave >> 1) == p) {
#pragma unroll
                for (int mt = 0; mt < 4; mt++)
#pragma unroll
                    for (int nt = 0; nt < 4; nt++) {
                        int c = nt * 16 + l16;
                        short4v pk;
                        pk.x = f2bf(acc[2][mt][nt][0] + bvv[nt]);
                        pk.y = f2bf(acc[2][mt][nt][1] + bvv[nt]);
                        pk.z = f2bf(acc[2][mt][nt][2] + bvv[nt]);
                        pk.w = f2bf(acc[2][mt][nt][3] + bvv[nt]);
                        *(short4v*)&buf[c * 72 + mt * 16 + quad * 4] = pk;
                    }
                asm volatile("s_waitcnt lgkmcnt(0)" ::: "memory");
#pragma unroll
                for (int ps = 0; ps < 8; ps++) {
                    int dl = ps * 8 + (lane >> 3);
                    int sl = (lane & 7) * 8;
                    short8 row = *(short8*)&buf[dl * 72 + sl];
                    *(short8*)(vt + (size_t)dl * S_LEN + sbase + sl) = row;
                }
            }
        }
    }
}

// scores -> P = exp(s) (bf16, causal-masked) + per-row denom accumulation.
// BK=128; heavy-first dispatch (xq reversed -> it descending per batch) so the
// 32 non-resident straggler blocks are 1-iter it=0 tiles, not 8-iter it=15.
__global__ __launch_bounds__(256, 2)
void score_gemm(const short* __restrict__ Qb, const short* __restrict__ Kb,
                short* __restrict__ P, float* __restrict__ denom) {
    __shared__ short As[16384];
    __shared__ short Bs[16384];
    int b = blockIdx.z;
    int xq = 135 - (int)blockIdx.x;    // heavy-first
    int it = (int)((sqrtf(8.0f * xq + 1.0f) - 1.0f) * 0.5f);
    while ((it + 1) * (it + 2) / 2 <= xq) it++;
    while (it * (it + 1) / 2 > xq) it--;
    int jt = xq - it * (it + 1) / 2;
    int n0 = jt * 128, m0 = it * 128;
    const short* A  = Qb + (size_t)b * S_LEN * DM;
    const short* Bt = Kb + (size_t)b * S_LEN * DM;

    floatx4 acc[4][4];
#pragma unroll
    for (int i = 0; i < 4; i++)
#pragma unroll
        for (int j = 0; j < 4; j++) acc[i][j] = (floatx4){0.f, 0.f, 0.f, 0.f};

    gemm_core128(A, Bt, DM, DM, DM, m0, n0, acc, As, Bs);

    short* out = P + (size_t)b * S_LEN * S_LEN;
    float* dsum = denom + (size_t)b * S_LEN;
    const int lane = threadIdx.x & 63, wave = threadIdx.x >> 6;
    const int wr = (wave >> 1) * 64, wc = (wave & 1) * 64;
    const int quad = lane >> 4, l16 = lane & 15;
    const bool diag = (jt == it);
#pragma unroll
    for (int mt = 0; mt < 4; mt++) {
#pragma unroll
        for (int r = 0; r < 4; r++) {
            int row = m0 + wr + mt * 16 + quad * 4 + r;
            float psum = 0.f;
#pragma unroll
            for (int nt = 0; nt < 4; nt++) {
                int col = n0 + wc + nt * 16 + l16;
                float e = __expf(acc[mt][nt][r]);
                if (diag && col > row) e = 0.f;
                out[(size_t)row * S_LEN + col] = f2bf(e);
                psum += e;
            }
#pragma unroll
            for (int off = 8; off > 0; off >>= 1)
                psum += __shfl_down(psum, off, 16);
            if (l16 == 0) atomicAdd(&dsum[row], psum);
        }
    }
}

// ---------------- PV GEMM, BK=128, 1-D longest-first grid (R9 config) ------
// bid -> it = 15 - (bid>>5) (heaviest first), dc = (bid>>2)&7, b = bid&3.
__global__ __launch_bounds__(256, 2)
void pv_gemm(const short* __restrict__ P, const short* __restrict__ Vtb,
             const float* __restrict__ denom, float* __restrict__ O) {
    __shared__ short As[16384];
    __shared__ short Bs[16384];
    int bid = blockIdx.x;
    int it = 15 - (bid >> 5);          // all 32 it=15 blocks dispatch first
    int n0 = ((bid >> 2) & 7) * 128;   // d
    int b  = bid & 3;
    int m0 = it * 128;                 // query rows
    int kLen = (it + 1) * 128;         // causal clip
    const short* A  = P   + (size_t)b * S_LEN * S_LEN;
    const short* Bt = Vtb + (size_t)b * DM * S_LEN;

    floatx4 acc[4][4];
#pragma unroll
    for (int i = 0; i < 4; i++)
#pragma unroll
        for (int j = 0; j < 4; j++) acc[i][j] = (floatx4){0.f, 0.f, 0.f, 0.f};

    gemm_core128(A, Bt, S_LEN, S_LEN, kLen, m0, n0, acc, As, Bs);

    float* out = O + (size_t)b * S_LEN * DM;
    const float* dsum = denom + (size_t)b * S_LEN;
    const int lane = threadIdx.x & 63, wave = threadIdx.x >> 6;
    const int wr = (wave >> 1) * 64, wc = (wave & 1) * 64;
    const int quad = lane >> 4, l16 = lane & 15;
#pragma unroll
    for (int mt = 0; mt < 4; mt++) {
#pragma unroll
        for (int r = 0; r < 4; r++) {
            int row = m0 + wr + mt * 16 + quad * 4 + r;
            float inv = 1.0f / dsum[row];
#pragma unroll
            for (int nt = 0; nt < 4; nt++) {
                int col = n0 + wc + nt * 16 + l16;
                out[(size_t)row * DM + col] = acc[mt][nt][r] * inv;
            }
        }
    }
}

// ---------------- launch ----------------
extern "C" void kernel_launch(void* const* d_in, const int* in_sizes, int n_in,
                              void* d_out, int out_size, void* d_ws, size_t ws_size,
                              hipStream_t stream) {
    const float* x  = (const float*)d_in[0];
    const float* Wq = (const float*)d_in[1];
    const float* bq = (const float*)d_in[2];
    const float* Wk = (const float*)d_in[3];
    const float* bk = (const float*)d_in[4];
    const float* Wv = (const float*)d_in[5];
    const float* bv = (const float*)d_in[6];
    float* out = (float*)d_out;

    char* ws = (char*)d_ws;
    const size_t MB = 1u << 20;
    short* xb    = (short*)(ws + 0);          // 16 MB  [8192][1024] bf16
    short* Wt    = (short*)(ws + 16 * MB);    //  6 MB  [3][1024][1024] bf16 (n-major)
    short* Qb    = (short*)(ws + 22 * MB);    // 16 MB
    short* Kb    = (short*)(ws + 38 * MB);    // 16 MB
    short* Vtb   = (short*)(ws + 54 * MB);    // 16 MB  [b][d][s]
    short* P     = (short*)(ws + 70 * MB);    // 32 MB  [b][s][s] bf16 = exp(s)
    float* denom = (float*)(ws + 102 * MB);   // 32 KB  [b][s] fp32 row sums
    // total ~102 MB

    prep<<<dim3(8992), dim3(256), 0, stream>>>(x, Wq, Wk, Wv, xb, Wt, denom);
    qkv_fused<<<dim3(8, 64), dim3(256), 0, stream>>>(xb, Wt, bq, bk, bv, Qb, Kb, Vtb);
    score_gemm<<<dim3(136, 1, NB), dim3(256), 0, stream>>>(Qb, Kb, P, denom);
    pv_gemm<<<dim3(512), dim3(256), 0, stream>>>(P, Vtb, denom, out);
}